// Round 5
// baseline (268.007 us; speedup 1.0000x reference)
//
#include <hip/hip_runtime.h>
#include <math.h>

#define NB 16
#define NC 64
#define HW 160
#define PLANE (HW * HW)               // 25600
#define SG 161                        // site grid (H+1)
#define SGSQ (SG * SG)                // 25921
#define NSITES (NB * SGSQ)            // 414736
#define OUT_LD_OFF (NB * NC * PLANE)  // logdet output offset
#define TILE 256                      // sites per conv block
#define NCONV ((NSITES + TILE - 1) / TILE)  // 1621

// Union shared memory: det block needs 6404 floats; conv vtile[16][256]=4096.
#define SMEM_FLOATS 6404

// Map local submatrix index -> channel index for the INDS masks.
__device__ inline int chmap(int i, int n, int pa, int pb) {
    if (n == 64) return i;
    if (n == 32) return ((i >> 1) << 2) | ((i & 1) ? pb : pa);
    return (i << 2) | pa;
}

// One wave factorizes an n x n submatrix of W (LU, partial pivoting) in its
// private LDS region A and returns log|det|. Wave-lockstep.
__device__ float wave_lu_logabsdet(const float* __restrict__ W, float* A,
                                   int n, int sh, int pa, int pb, int lane) {
    for (int e = lane; e < n * n; e += 64) {
        int i = e >> sh, j = e & (n - 1);
        A[e] = W[chmap(i, n, pa, pb) * 64 + chmap(j, n, pa, pb)];
    }
    asm volatile("s_waitcnt lgkmcnt(0) vmcnt(0)" ::: "memory");
    float logdet = 0.f;
    for (int k = 0; k < n; ++k) {
        float cand = -1.f;
        int idx = k;
        if (lane >= k && lane < n) {
            cand = fabsf(A[(lane << sh) + k]);
            idx = lane;
        }
        for (int off = 32; off; off >>= 1) {
            float oc = __shfl_down(cand, off, 64);
            int oi = __shfl_down(idx, off, 64);
            if (oc > cand) { cand = oc; idx = oi; }
        }
        int p = __shfl(idx, 0, 64);
        if (p != k && lane < n) {
            float tk = A[(k << sh) + lane];
            float tp = A[(p << sh) + lane];
            A[(k << sh) + lane] = tp;
            A[(p << sh) + lane] = tk;
        }
        asm volatile("s_waitcnt lgkmcnt(0)" ::: "memory");
        float piv = A[(k << sh) + k];
        logdet += logf(fabsf(piv));
        float rpiv = 1.f / piv;
        float ckj = (lane < n) ? A[(k << sh) + lane] : 0.f;
        bool act = (lane > k) && (lane < n);
        for (int i2 = k + 1; i2 < n; ++i2) {
            float aik = A[(i2 << sh) + k];
            float mult = aik * rpiv;
            if (act) A[(i2 << sh) + lane] = fmaf(-mult, ckj, A[(i2 << sh) + lane]);
        }
        asm volatile("s_waitcnt lgkmcnt(0)" ::: "memory");
    }
    return logdet;
}

__global__ __launch_bounds__(256, 4) void InvConv1x1GridAlign_kernel(
    const float* __restrict__ x, const float* __restrict__ ld_in,
    const float* __restrict__ W, float* __restrict__ out) {
    __shared__ __align__(16) float smem[SMEM_FLOATS];
    const int tid = threadIdx.x;

    if (blockIdx.x == 0) {
        // ---- determinant block: 9 slogdets, one wave per matrix group ----
        float* A64 = smem;
        float* A32a = smem + 4096;
        float* A32b = smem + 5120;
        float* A16 = smem + 6144;
        float* partial = smem + 6400;
        int wid = tid >> 6;
        int lane = tid & 63;
        float part = 0.f;
        if (wid == 0) {
            part = 25281.f * wave_lu_logabsdet(W, A64, 64, 6, 0, 0, lane);
        } else if (wid == 1) {
            part  = wave_lu_logabsdet(W, A32a, 32, 5, 2, 3, lane);
            part += wave_lu_logabsdet(W, A32a, 32, 5, 0, 1, lane);
            part *= 159.f;
        } else if (wid == 2) {
            part  = wave_lu_logabsdet(W, A32b, 32, 5, 1, 3, lane);
            part += wave_lu_logabsdet(W, A32b, 32, 5, 0, 2, lane);
            part *= 159.f;
        } else {
            part  = wave_lu_logabsdet(W, A16, 16, 4, 3, 0, lane);
            part += wave_lu_logabsdet(W, A16, 16, 4, 2, 0, lane);
            part += wave_lu_logabsdet(W, A16, 16, 4, 1, 0, lane);
            part += wave_lu_logabsdet(W, A16, 16, 4, 0, 0, lane);
        }
        if (lane == 0) partial[wid] = part;
        __syncthreads();
        if (tid < NB) {
            float dl = partial[0] + partial[1] + partial[2] + partial[3];
            out[OUT_LD_OFF + tid] = ld_in[tid] + dl;
        }
        return;
    }

    // ---- conv blocks: GEMM tile, 64 outputs x 256 sites ----
    // u[o][s] = sum_k W[o][k] * v[k][s]; v[k][s] = x[b][k^3][Y-1+dy][X-1+dx]
    // (dy=(k>>1)&1, dx=k&1; quadrant m = k&3). k split into 4 quarters of 16;
    // per quarter, v staged via UNCONDITIONAL clamped loads (x mask at LDS
    // write) double-buffered in rv[16]: next quarter's loads issue before this
    // quarter's compute, hiding L3 latency under ~2K cycles of FMA (T14).
    const int tile0 = ((int)blockIdx.x - 1) * TILE;
    const int lane = tid & 63;
    const int wid = tid >> 6;
    const int wo = __builtin_amdgcn_readfirstlane(wid << 4);  // wave-uniform

    // per-thread staging site decode (site = tile0 + tid)
    int aoffm[4];   // clamped in-bounds plane offset per quadrant
    float msk[4];   // 1.0 valid / 0.0 invalid
    const float* xb;
    {
        const int offm[4] = {0, 1, HW, HW + 1};
        int s = tile0 + tid;
        bool sok = s < NSITES;
        unsigned us = (unsigned)(sok ? s : 0);
        unsigned b = us / SGSQ;
        unsigned rr = us - b * SGSQ;
        unsigned Y = rr / SG;
        unsigned X = rr - Y * SG;
        xb = x + (size_t)b * (NC * PLANE);
        int baseoff = ((int)Y - 1) * HW + ((int)X - 1);
        bool okT = sok && (Y >= 1), okB = sok && (Y <= HW - 1);
        bool okL = (X >= 1), okR = (X <= HW - 1);
        bool vm[4] = {okT && okL, okT && okR, okB && okL, okB && okR};
#pragma unroll
        for (int m = 0; m < 4; ++m) {
            aoffm[m] = vm[m] ? (baseoff + offm[m]) : 0;
            msk[m] = vm[m] ? 1.f : 0.f;
        }
    }

    float acc[16][4];
#pragma unroll
    for (int j = 0; j < 16; ++j)
#pragma unroll
        for (int s2 = 0; s2 < 4; ++s2) acc[j][s2] = 0.f;

    // prologue: issue quarter-0 loads (unconditional, coalesced)
    float rv[16];
#pragma unroll
    for (int j = 0; j < 16; ++j) {
        const int pl = j ^ 3;  // plane for k = j
        rv[j] = xb[pl * PLANE + aoffm[j & 3]];
    }

#pragma unroll 1
    for (int q = 0; q < 4; ++q) {
        __syncthreads();  // previous compute done before overwriting vtile
        // ---- write staged quarter: 16 ds_write_b32, mask applied here ----
#pragma unroll
        for (int j = 0; j < 16; ++j)
            smem[(j << 8) + tid] = msk[j & 3] * rv[j];
        __syncthreads();
        // ---- issue next quarter's loads; they ride out under compute ----
        if (q < 3) {
#pragma unroll
            for (int j = 0; j < 16; ++j) {
                const int k = ((q + 1) << 4) + j;
                const int pl = k ^ 3;
                rv[j] = xb[pl * PLANE + aoffm[j & 3]];
            }
        }
        // ---- compute 4 k-steps x 4: 16 ds_read_b32 + wave-uniform W ----
#pragma unroll 1
        for (int kb = 0; kb < 4; ++kb) {
            float v[4][4];
            const float* vb = smem + (kb << 10) + lane;
#pragma unroll
            for (int kk = 0; kk < 4; ++kk)
#pragma unroll
                for (int s2 = 0; s2 < 4; ++s2)
                    v[kk][s2] = vb[(kk << 8) + (s2 << 6)];
            const int k0 = (q << 4) + (kb << 2);
#pragma unroll
            for (int jb = 0; jb < 2; ++jb) {
                float4 w4[8];  // wave-uniform -> s_load_dwordx4 from K$
#pragma unroll
                for (int j = 0; j < 8; ++j)
                    w4[j] = *(const float4*)(W + (wo + (jb << 3) + j) * 64 + k0);
#pragma unroll
                for (int j = 0; j < 8; ++j) {
                    const int jj = (jb << 3) + j;
#pragma unroll
                    for (int kk = 0; kk < 4; ++kk) {
                        const float wjk = (kk == 0) ? w4[j].x
                                        : (kk == 1) ? w4[j].y
                                        : (kk == 2) ? w4[j].z : w4[j].w;
#pragma unroll
                        for (int s2 = 0; s2 < 4; ++s2)
                            acc[jj][s2] = fmaf(wjk, v[kk][s2], acc[jj][s2]);
                    }
                }
            }
        }
    }

    // ---- epilogue: lane's 4 sites are stride-64 -> coalesced stores ----
#pragma unroll
    for (int s2 = 0; s2 < 4; ++s2) {
        int s = tile0 + lane + (s2 << 6);
        bool sok = s < NSITES;
        unsigned us = (unsigned)(sok ? s : 0);
        unsigned b = us / SGSQ;
        unsigned rr = us - b * SGSQ;
        unsigned Y = rr / SG;
        unsigned X = rr - Y * SG;
        float* ob = out + (size_t)b * (NC * PLANE);
        int boff = ((int)Y - 1) * HW + ((int)X - 1);
        bool okT = sok && (Y >= 1), okB = sok && (Y <= HW - 1);
        bool okL = (X >= 1), okR = (X <= HW - 1);
        bool wm[4] = {okT && okL, okT && okR, okB && okL, okB && okR};
        const int offm[4] = {0, 1, HW, HW + 1};
#pragma unroll
        for (int j = 0; j < 16; ++j) {
            const int o = wo + j;
            const int pl = o ^ 3;
            const int m = j & 3;  // o mod 4 (wo multiple of 16)
            if (wm[m]) ob[pl * PLANE + boff + offm[m]] = acc[j][s2];
        }
    }
}

extern "C" void kernel_launch(void* const* d_in, const int* in_sizes, int n_in,
                              void* d_out, int out_size, void* d_ws, size_t ws_size,
                              hipStream_t stream) {
    const float* x = (const float*)d_in[0];
    const float* ld = (const float*)d_in[1];
    const float* W = (const float*)d_in[2];
    float* out = (float*)d_out;
    hipLaunchKernelGGL(InvConv1x1GridAlign_kernel, dim3(NCONV + 1), dim3(256), 0,
                       stream, x, ld, W, out);
}